// Round 8
// baseline (1081.731 us; speedup 1.0000x reference)
//
#include <hip/hip_runtime.h>

// Zero-phase bandpass FIR = one 8191-tap correlation with the kernel
// autocorrelation g:  out[j][t] = sum_s g[s]*xe[j][t+s]  (g bf16-hi, x bf16).
// Round 8: r7's 32x32x16 A-reuse ring, register-sized to actually fit.
// Tile = 32 t x 32 rows. A_c[m][k]=g[16c+k-m]; B_W[k][j]=xe[j][16(8bx+W)+k].
// Tile mt at window W uses c = W-2mt and the same B_W. Wave = one K-quarter
// of 4 tiles: per W-step 1 B ds_read + 1 A ring-refill + 4 MFMAs.
// Ring depth 12 (48 VGPR, compile-time slots via period-6 template),
// acc[4] f32x16 -> AGPR. Block = 4 waves (4 cq), LDS phased combine.

#define T_LEN  131072
#define NW     8720          // xeT windows (16 t each)
#define WQ     132           // W-steps per c-quarter (4*132 = 528 total)
#define NSS    33            // supersteps of 4 W per quarter
#define NATAB  544           // A chunks, idx = c + 8

typedef float  f32x4  __attribute__((ext_vector_type(4)));
typedef float  f32x16 __attribute__((ext_vector_type(16)));
typedef __bf16 bf16x8 __attribute__((ext_vector_type(8)));

// ---------- ws layout (bytes) ----------
#define WS_G    0            // 8192 floats (autocorrelation)
#define WS_ATAB 32768        // 544*1024 B bf16 Toeplitz frags
#define WS_XET  589824       // 8720*1024 B window-major swizzled signal
#define WS_END  9519104

__device__ __forceinline__ void gload_lds16(const uint4* g, uint4* lds) {
  __builtin_amdgcn_global_load_lds(
      (const __attribute__((address_space(1))) unsigned int*)g,
      (__attribute__((address_space(3))) unsigned int*)lds, 16, 0, 0);
}

// K1: xeT build (+ zero g). Window v: logical slot u = 2j + q8 holds
// xe_row_j[16v + 8*q8 + 0..8) as bf16; stored at phys slot p = u^((u>>3)&7).
__global__ void k_build_xeT(const float* __restrict__ x, uint4* __restrict__ xeT,
                            float* __restrict__ g) {
  int idx = blockIdx.x * 256 + threadIdx.x;
  if (idx < 2048) *(float4*)((float*)g + idx * 4) = make_float4(0.f, 0.f, 0.f, 0.f);
  if (idx >= NW * 64) return;
  int v = idx >> 6, pp = idx & 63;
  int u = pp ^ ((pp >> 3) & 7);
  int j = u >> 1, q8 = u & 1;
  const float* xr = x + (size_t)j * T_LEN;
  int w0 = (v << 4) + (q8 << 3);
  int v0 = w0 - 4095;                       // xe[w] = X(w-4095)
  bf16x8 o;
  if (v0 >= 0 && v0 <= T_LEN - 8) {
    float4 f0, f1;
    __builtin_memcpy(&f0, xr + v0, 16);
    __builtin_memcpy(&f1, xr + v0 + 4, 16);
    o[0] = (__bf16)f0.x; o[1] = (__bf16)f0.y; o[2] = (__bf16)f0.z; o[3] = (__bf16)f0.w;
    o[4] = (__bf16)f1.x; o[5] = (__bf16)f1.y; o[6] = (__bf16)f1.z; o[7] = (__bf16)f1.w;
  } else {
    #pragma unroll
    for (int e = 0; e < 8; ++e) {
      int vv = v0 + e;
      float val = 0.0f;
      if (vv >= -2048 && vv < T_LEN + 2048) {
        int v2 = vv < 0 ? -vv : vv;
        v2 = v2 >= T_LEN ? 2 * T_LEN - 2 - v2 : v2;
        val = xr[v2];
      }
      o[e] = (__bf16)val;
    }
  }
  xeT[(size_t)v * 64 + pp] = __builtin_bit_cast(uint4, o);
}

// K2: autocorr direct from k. g[s] = sum_{i<=s} k[i]*k[i+4095-s], mirrored.
__global__ void k_autocorr(const float* __restrict__ k, float* __restrict__ g) {
  int s = blockIdx.x * 256 + threadIdx.x;   // [0, 4096)
  int i0 = blockIdx.y * 256;
  int d = 4095 - s;
  float a0 = 0.f, a1 = 0.f, a2 = 0.f, a3 = 0.f;
  #pragma unroll 4
  for (int i = 0; i < 256; i += 4) {
    int b = i0 + i;
    if (b + 0 <= s) a0 = fmaf(k[b + 0], k[b + 0 + d], a0);
    if (b + 1 <= s) a1 = fmaf(k[b + 1], k[b + 1 + d], a1);
    if (b + 2 <= s) a2 = fmaf(k[b + 2], k[b + 2 + d], a2);
    if (b + 3 <= s) a3 = fmaf(k[b + 3], k[b + 3 + d], a3);
  }
  float part = (a0 + a1) + (a2 + a3);
  atomicAdd(&g[s], part);
  if (s != 4095) atomicAdd(&g[8190 - s], part);
}

// K3: A-table, fragment-ordered [cidx][lane][8 bf16], cidx = c + 8.
// Lane l: m = l&31, k = (l>>5)*8 + jj; val = g[16c + k - m] (0 outside).
__global__ void k_build_atab(const float* __restrict__ g, __bf16* __restrict__ A) {
  int cidx = blockIdx.x;
  int t = threadIdx.x;
  int l = t >> 2, jj0 = (t & 3) * 2;
  int m = l & 31, q8 = l >> 5;
  int c = cidx - 8;
  #pragma unroll
  for (int e = 0; e < 2; ++e) {
    int kk = (q8 << 3) + jj0 + e;
    int s = 16 * c + kk - m;
    float val = (s >= 0 && s <= 8190) ? g[s] : 0.0f;
    A[(size_t)cidx * 512 + l * 8 + jj0 + e] = (__bf16)val;
  }
}

// One 4-W superstep. PA = (ss%3)*4 (A-ring phase, depth 12); PB = (ss&1)*4
// (B double-buffer phase, 8 slots). All ring indices compile-time.
template <int PA, int PB>
__device__ __forceinline__ void superstep(
    int ss, const uint4* __restrict__ bsrc, const uint4* __restrict__ asrc,
    uint4* __restrict__ ring, int p, uint4 (&Areg)[12], f32x16 (&acc)[4]) {
  asm volatile("s_waitcnt vmcnt(0)" ::: "memory");   // this ss's B + A refills ready
  if (ss + 1 < NSS) {                                // async-stage next 4 B windows
    const uint4* bs = bsrc + ((size_t)(ss + 1) << 8);
    uint4* rs = ring + ((PB ^ 4) << 6);
    #pragma unroll
    for (int i = 0; i < 4; ++i)
      gload_lds16(bs + (i << 6), rs + (i << 6));
  }
  #pragma unroll
  for (int i = 0; i < 4; ++i) {
    const int Wl = 4 * ss + i;
    bf16x8 B = __builtin_bit_cast(bf16x8, ring[((PB + i) << 6) + p]);
    #pragma unroll
    for (int mt = 0; mt < 4; ++mt) {
      const int sl = ((PA + i - 2 * mt) % 12 + 12) % 12;
      bf16x8 A = __builtin_bit_cast(bf16x8, Areg[sl]);
      acc[mt] = __builtin_amdgcn_mfma_f32_32x32x16_bf16(A, B, acc[mt], 0, 0, 0);
    }
    // refill slot just freed (A(Wl-6) dead after step Wl); used at Wl+6
    Areg[(PA + i + 6) % 12] = asrc[(ptrdiff_t)(Wl + 6) * 64];
  }
}

// Main: 256 thr = 4 waves = 4 c-quarters (cq) of the SAME 4 tiles (128 t).
// Grid 1024 blocks; 12 waves/CU at launch_bounds(256,3). Per-wave private
// 8-slot LDS B ring (8 KB) staged by global_load_lds; 12-deep A register
// ring; no barriers in main loop; 4-phase LDS combine + coalesced store.
__global__ __launch_bounds__(256, 3) void k_fir_mfma(
    const uint4* __restrict__ xeT, const uint4* __restrict__ Atab,
    float* __restrict__ out) {
  __shared__ uint4 smem[2048];               // 4 waves x 8 slots x 1 KB = 32 KB

  const int tid = threadIdx.x;
  const int cq = tid >> 6;
  const int l = tid & 63, j = l & 31, q8 = l >> 5;
  const int bx = blockIdx.x, t0b = bx << 7;  // 128 t per block
  const int u = (j << 1) | q8;
  const int p = u ^ ((u >> 3) & 7);          // swizzled B slot (conflict-free)
  const int Wcq = cq * WQ;

  const uint4* bsrc = xeT + ((size_t)((bx << 3) + Wcq) << 6) + l;
  const uint4* asrc = Atab + ((size_t)(Wcq + 8) << 6) + l;
  uint4* ring = smem + (cq << 9);

  f32x16 acc[4];
  {
    f32x16 z;
    #pragma unroll
    for (int e = 0; e < 16; ++e) z[e] = 0.f;
    #pragma unroll
    for (int mt = 0; mt < 4; ++mt) acc[mt] = z;
  }

  uint4 Areg[12];
  // prologue: stage ss=0's B slots; fill A ring for Wl in [-6, 6)
  #pragma unroll
  for (int i = 0; i < 4; ++i)
    gload_lds16(bsrc + (i << 6), ring + (i << 6));
  #pragma unroll
  for (int w = -6; w < 6; ++w)
    Areg[(w + 12) % 12] = asrc[(ptrdiff_t)w * 64];

  for (int ss = 0; ss < NSS; ++ss) {
    switch (ss % 6) {
      case 0:  superstep<0, 0>(ss, bsrc, asrc, ring, p, Areg, acc); break;
      case 1:  superstep<4, 4>(ss, bsrc, asrc, ring, p, Areg, acc); break;
      case 2:  superstep<8, 0>(ss, bsrc, asrc, ring, p, Areg, acc); break;
      case 3:  superstep<0, 4>(ss, bsrc, asrc, ring, p, Areg, acc); break;
      case 4:  superstep<4, 0>(ss, bsrc, asrc, ring, p, Areg, acc); break;
      default: superstep<8, 4>(ss, bsrc, asrc, ring, p, Areg, acc); break;
    }
  }

  // ---- combine 4 c-quarters in LDS (phased), then coalesced store ----
  // C/D 32x32: col = j = lane&31, row m = (reg&3) + 8*(reg>>2) + 4*(lane>>5).
  __syncthreads();                           // rings dead
  float* Cf = (float*)smem;                  // 4 tiles x 32j x 36m floats
  const int co = j * 36 + (q8 << 2);
  #pragma unroll 1
  for (int ph = 0; ph < 4; ++ph) {
    if (cq == ph) {
      #pragma unroll
      for (int mt = 0; mt < 4; ++mt) {
        float* cp = Cf + mt * 1152 + co;
        #pragma unroll
        for (int rq = 0; rq < 4; ++rq) {
          f32x4 v;
          v[0] = acc[mt][4 * rq + 0]; v[1] = acc[mt][4 * rq + 1];
          v[2] = acc[mt][4 * rq + 2]; v[3] = acc[mt][4 * rq + 3];
          float* dst = cp + (rq << 3);
          if (ph != 0) v += *(const f32x4*)dst;
          *(f32x4*)dst = v;
        }
      }
    }
    __syncthreads();
  }
  {
    const int row = tid >> 1;                // 0..127: tile mt = row>>5, j = row&31
    const int mt = row >> 5, j2 = row & 31, h = tid & 1;
    const float* src = Cf + mt * 1152 + j2 * 36 + (h << 4);
    float* dst = out + (size_t)j2 * T_LEN + t0b + (mt << 5) + (h << 4);
    #pragma unroll
    for (int w4 = 0; w4 < 4; ++w4)
      *(f32x4*)(dst + (w4 << 2)) = *(const f32x4*)(src + (w4 << 2));
  }
}

extern "C" void kernel_launch(void* const* d_in, const int* in_sizes, int n_in,
                              void* d_out, int out_size, void* d_ws, size_t ws_size,
                              hipStream_t stream) {
  const float* x = (const float*)d_in[0];
  const float* k = (const float*)d_in[1];
  float* out = (float*)d_out;
  char* ws = (char*)d_ws;
  if (ws_size < (size_t)WS_END) return;

  float*  g    = (float*)(ws + WS_G);
  __bf16* Atab = (__bf16*)(ws + WS_ATAB);
  uint4*  xeT  = (uint4*)(ws + WS_XET);

  k_build_xeT<<<dim3((NW * 64 + 255) / 256), dim3(256), 0, stream>>>(x, xeT, g);
  k_autocorr<<<dim3(16, 16), dim3(256), 0, stream>>>(k, g);
  k_build_atab<<<dim3(NATAB), dim3(256), 0, stream>>>(g, Atab);
  k_fir_mfma<<<dim3(1024), dim3(256), 0, stream>>>(
      xeT, (const uint4*)Atab, out);
}

// Round 9
// 963.809 us; speedup vs baseline: 1.1224x; 1.1224x over previous
//
#include <hip/hip_runtime.h>

// Zero-phase bandpass FIR = one 8191-tap correlation with the kernel
// autocorrelation g:  out[j][t] = sum_s g[s]*xe[j][t+s]  (g bf16-hi, x bf16).
// Round 9: r8's 32x32x16 A-reuse structure with the scratch bug fixed.
// SROA lesson: register arrays with non-constant indices (at SROA time) go
// to scratch -> A-ring is 12 NAMED uint4 vars, supersteps hand-unrolled
// (switch on ss%3); accs are 4 named f32x16; xeT slot order = lane order
// (no swizzle) so staging and ds_read are both identity / conflict-free.
// Wave = one c-quarter of 4 tiles (128 t x 32 rows); per W-step:
// 1 B ds_read_b128 + 1 A ring-refill (global, named reg) + 4 MFMAs.

#define T_LEN  131072
#define NW     8720          // xeT windows (16 t each)
#define WQ     132           // W-steps per c-quarter (4*132 = 528 total)
#define NSS    33            // supersteps of 4 W per quarter
#define NATAB  544           // A chunks, idx = c + 8

typedef float  f32x4  __attribute__((ext_vector_type(4)));
typedef float  f32x16 __attribute__((ext_vector_type(16)));
typedef __bf16 bf16x8 __attribute__((ext_vector_type(8)));

// ---------- ws layout (bytes) ----------
#define WS_G    0            // 8192 floats (autocorrelation)
#define WS_ATAB 32768        // 544*1024 B bf16 Toeplitz frags
#define WS_XET  589824       // 8720*1024 B window-major signal
#define WS_END  9519104

__device__ __forceinline__ void gload_lds16(const uint4* g, uint4* lds) {
  __builtin_amdgcn_global_load_lds(
      (const __attribute__((address_space(1))) unsigned int*)g,
      (__attribute__((address_space(3))) unsigned int*)lds, 16, 0, 0);
}

// K1: xeT build (+ zero g). Window v, phys slot pp = lane: j = pp&31,
// q8 = pp>>5; holds xe_row_j[16v + 8*q8 + 0..8) as bf16 (identity layout).
__global__ void k_build_xeT(const float* __restrict__ x, uint4* __restrict__ xeT,
                            float* __restrict__ g) {
  int idx = blockIdx.x * 256 + threadIdx.x;
  if (idx < 2048) *(float4*)((float*)g + idx * 4) = make_float4(0.f, 0.f, 0.f, 0.f);
  if (idx >= NW * 64) return;
  int v = idx >> 6, pp = idx & 63;
  int j = pp & 31, q8 = pp >> 5;
  const float* xr = x + (size_t)j * T_LEN;
  int w0 = (v << 4) + (q8 << 3);
  int v0 = w0 - 4095;                       // xe[w] = X(w-4095)
  bf16x8 o;
  if (v0 >= 0 && v0 <= T_LEN - 8) {
    float4 f0, f1;
    __builtin_memcpy(&f0, xr + v0, 16);
    __builtin_memcpy(&f1, xr + v0 + 4, 16);
    o[0] = (__bf16)f0.x; o[1] = (__bf16)f0.y; o[2] = (__bf16)f0.z; o[3] = (__bf16)f0.w;
    o[4] = (__bf16)f1.x; o[5] = (__bf16)f1.y; o[6] = (__bf16)f1.z; o[7] = (__bf16)f1.w;
  } else {
    #pragma unroll
    for (int e = 0; e < 8; ++e) {
      int vv = v0 + e;
      float val = 0.0f;
      if (vv >= -2048 && vv < T_LEN + 2048) {
        int v2 = vv < 0 ? -vv : vv;
        v2 = v2 >= T_LEN ? 2 * T_LEN - 2 - v2 : v2;
        val = xr[v2];
      }
      o[e] = (__bf16)val;
    }
  }
  xeT[(size_t)v * 64 + pp] = __builtin_bit_cast(uint4, o);
}

// K2: autocorr direct from k. g[s] = sum_{i<=s} k[i]*k[i+4095-s], mirrored.
__global__ void k_autocorr(const float* __restrict__ k, float* __restrict__ g) {
  int s = blockIdx.x * 256 + threadIdx.x;   // [0, 4096)
  int i0 = blockIdx.y * 256;
  int d = 4095 - s;
  float a0 = 0.f, a1 = 0.f, a2 = 0.f, a3 = 0.f;
  #pragma unroll 4
  for (int i = 0; i < 256; i += 4) {
    int b = i0 + i;
    if (b + 0 <= s) a0 = fmaf(k[b + 0], k[b + 0 + d], a0);
    if (b + 1 <= s) a1 = fmaf(k[b + 1], k[b + 1 + d], a1);
    if (b + 2 <= s) a2 = fmaf(k[b + 2], k[b + 2 + d], a2);
    if (b + 3 <= s) a3 = fmaf(k[b + 3], k[b + 3 + d], a3);
  }
  float part = (a0 + a1) + (a2 + a3);
  atomicAdd(&g[s], part);
  if (s != 4095) atomicAdd(&g[8190 - s], part);
}

// K3: A-table, fragment-ordered [cidx][lane][8 bf16], cidx = c + 8.
// Lane l: m = l&31, k = (l>>5)*8 + jj; val = g[16c + k - m] (0 outside).
__global__ void k_build_atab(const float* __restrict__ g, __bf16* __restrict__ A) {
  int cidx = blockIdx.x;
  int t = threadIdx.x;
  int l = t >> 2, jj0 = (t & 3) * 2;
  int m = l & 31, q8 = l >> 5;
  int c = cidx - 8;
  #pragma unroll
  for (int e = 0; e < 2; ++e) {
    int kk = (q8 << 3) + jj0 + e;
    int s = 16 * c + kk - m;
    float val = (s >= 0 && s <= 8190) ? g[s] : 0.0f;
    A[(size_t)cidx * 512 + l * 8 + jj0 + e] = (__bf16)val;
  }
}

#define MF(accv, Av, Bv)                                                       \
  accv = __builtin_amdgcn_mfma_f32_32x32x16_bf16(                              \
      __builtin_bit_cast(bf16x8, Av), Bv, accv, 0, 0, 0)

// step i of a superstep: 1 B ds_read, 4 MFMAs on named A slots, 1 refill
#define STEP(i, sA, sB, sC, sD, REF)                                           \
  do {                                                                         \
    bf16x8 Bv = __builtin_bit_cast(bf16x8, bw[(i) << 6]);                      \
    MF(acc0, sA, Bv);                                                          \
    MF(acc1, sB, Bv);                                                          \
    MF(acc2, sC, Bv);                                                          \
    MF(acc3, sD, Bv);                                                          \
    REF = aref[(i) << 6];                                                      \
  } while (0)

// Main: 256 thr = 4 waves = 4 c-quarters (cq) of the SAME 4 tiles (128 t).
// Grid 1024 blocks; 12 waves/CU at launch_bounds(256,3). Per-wave private
// 8-slot LDS B ring (8 KB) staged by global_load_lds (identity layout);
// 12-deep NAMED A register ring; no barriers in main loop; phased LDS
// combine with compile-time acc indices + coalesced store.
__global__ __launch_bounds__(256, 3) void k_fir_mfma(
    const uint4* __restrict__ xeT, const uint4* __restrict__ Atab,
    float* __restrict__ out) {
  __shared__ uint4 smem[2048];               // 4 waves x 8 slots x 1 KB = 32 KB

  const int tid = threadIdx.x;
  const int cq = tid >> 6;
  const int l = tid & 63, j = l & 31, q8 = l >> 5;
  const int bx = blockIdx.x, t0b = bx << 7;  // 128 t per block
  const int Wcq = cq * WQ;

  const uint4* bsrc = xeT + ((size_t)((bx << 3) + Wcq) << 6) + l;
  const uint4* asrc = Atab + ((size_t)(Wcq + 8) << 6) + l;
  uint4* ring = smem + (cq << 9);

  f32x16 acc0, acc1, acc2, acc3;
  {
    f32x16 z;
    #pragma unroll
    for (int e = 0; e < 16; ++e) z[e] = 0.f;
    acc0 = z; acc1 = z; acc2 = z; acc3 = z;
  }

  // prologue: stage ss=0's B slots (identity); fill A ring for chunks -6..5
  #pragma unroll
  for (int i = 0; i < 4; ++i)
    gload_lds16(bsrc + (i << 6), ring + (i << 6));
  uint4 A6  = asrc[-6 * 64], A7  = asrc[-5 * 64], A8  = asrc[-4 * 64];
  uint4 A9  = asrc[-3 * 64], A10 = asrc[-2 * 64], A11 = asrc[-1 * 64];
  uint4 A0  = asrc[0 * 64],  A1  = asrc[1 * 64],  A2  = asrc[2 * 64];
  uint4 A3  = asrc[3 * 64],  A4  = asrc[4 * 64],  A5  = asrc[5 * 64];

  for (int ss = 0; ss < NSS; ++ss) {
    asm volatile("s_waitcnt vmcnt(0)" ::: "memory");   // this ss's B ready
    const int PB = (ss & 1) << 2;
    if (ss + 1 < NSS) {                                // async-stage next 4 B
      const uint4* bs = bsrc + ((size_t)(ss + 1) << 8);
      uint4* rs = ring + ((PB ^ 4) << 6);
      #pragma unroll
      for (int i = 0; i < 4; ++i)
        gload_lds16(bs + (i << 6), rs + (i << 6));
    }
    const uint4* bw = ring + (PB << 6) + l;
    const uint4* aref = asrc + ((ptrdiff_t)(4 * ss + 6) << 6);
    switch (ss % 3) {
      case 0:                                          // A-phase 0
        STEP(0, A0, A10, A8,  A6,  A6);
        STEP(1, A1, A11, A9,  A7,  A7);
        STEP(2, A2, A0,  A10, A8,  A8);
        STEP(3, A3, A1,  A11, A9,  A9);
        break;
      case 1:                                          // A-phase 4
        STEP(0, A4, A2,  A0,  A10, A10);
        STEP(1, A5, A3,  A1,  A11, A11);
        STEP(2, A6, A4,  A2,  A0,  A0);
        STEP(3, A7, A5,  A3,  A1,  A1);
        break;
      default:                                         // A-phase 8
        STEP(0, A8,  A6, A4,  A2,  A2);
        STEP(1, A9,  A7, A5,  A3,  A3);
        STEP(2, A10, A8, A6,  A4,  A4);
        STEP(3, A11, A9, A7,  A5,  A5);
        break;
    }
  }

  // ---- combine 4 c-quarters in LDS (phased, compile-time indices) ----
  // C/D 32x32: col = j = lane&31, row m = (reg&3) + 8*(reg>>2) + 4*(lane>>5).
  __syncthreads();                           // rings dead
  float* Cf = (float*)smem;                  // 4 tiles x 32j x 36m floats
  const int co = j * 36 + (q8 << 2);
#define WRITE_TILE(mt, accv, ph)                                               \
  {                                                                            \
    float* cp = Cf + (mt) * 1152 + co;                                         \
    _Pragma("unroll") for (int rq = 0; rq < 4; ++rq) {                         \
      f32x4 v;                                                                 \
      v[0] = accv[4 * rq + 0]; v[1] = accv[4 * rq + 1];                        \
      v[2] = accv[4 * rq + 2]; v[3] = accv[4 * rq + 3];                        \
      float* dst = cp + (rq << 3);                                             \
      if ((ph) != 0) v += *(const f32x4*)dst;                                  \
      *(f32x4*)dst = v;                                                        \
    }                                                                          \
  }
  #pragma unroll 1
  for (int ph = 0; ph < 4; ++ph) {
    if (cq == ph) {
      WRITE_TILE(0, acc0, ph);
      WRITE_TILE(1, acc1, ph);
      WRITE_TILE(2, acc2, ph);
      WRITE_TILE(3, acc3, ph);
    }
    __syncthreads();
  }
  {
    const int row = tid >> 1;                // 0..127: (mt, j2); h = half
    const int mt = row >> 5, j2 = row & 31, h = tid & 1;
    const float* src = Cf + mt * 1152 + j2 * 36 + (h << 4);
    float* dst = out + (size_t)j2 * T_LEN + t0b + (mt << 5) + (h << 4);
    #pragma unroll
    for (int w4 = 0; w4 < 4; ++w4)
      *(f32x4*)(dst + (w4 << 2)) = *(const f32x4*)(src + (w4 << 2));
  }
}

extern "C" void kernel_launch(void* const* d_in, const int* in_sizes, int n_in,
                              void* d_out, int out_size, void* d_ws, size_t ws_size,
                              hipStream_t stream) {
  const float* x = (const float*)d_in[0];
  const float* k = (const float*)d_in[1];
  float* out = (float*)d_out;
  char* ws = (char*)d_ws;
  if (ws_size < (size_t)WS_END) return;

  float*  g    = (float*)(ws + WS_G);
  __bf16* Atab = (__bf16*)(ws + WS_ATAB);
  uint4*  xeT  = (uint4*)(ws + WS_XET);

  k_build_xeT<<<dim3((NW * 64 + 255) / 256), dim3(256), 0, stream>>>(x, xeT, g);
  k_autocorr<<<dim3(16, 16), dim3(256), 0, stream>>>(k, g);
  k_build_atab<<<dim3(NATAB), dim3(256), 0, stream>>>(g, Atab);
  k_fir_mfma<<<dim3(1024), dim3(256), 0, stream>>>(
      xeT, (const uint4*)Atab, out);
}